// Round 17
// baseline (826.697 us; speedup 1.0000x reference)
//
#include <hip/hip_runtime.h>
#include <stdint.h>

#define NGRAPH 1000

typedef __attribute__((ext_vector_type(8))) short short8;
typedef __attribute__((ext_vector_type(4))) float f32x4;

// ---------- helpers ----------
static __device__ __forceinline__ uint32_t pack2_bf16(float a, float b) {
  uint32_t ua = __float_as_uint(a), ub = __float_as_uint(b);
  ua = (ua + 0x7fffu + ((ua >> 16) & 1u)) >> 16;   // RNE
  ub = (ub + 0x7fffu + ((ub >> 16) & 1u)) >> 16;
  return ua | (ub << 16);
}
static __device__ __forceinline__ unsigned short f2bf(float x) {
  uint32_t u = __float_as_uint(x);
  u = (u + 0x7fffu + ((u >> 16) & 1u)) >> 16;
  return (unsigned short)u;
}
static __device__ __forceinline__ float bf2f(unsigned short u) {
  return __uint_as_float(((uint32_t)u) << 16);
}
union frag_u { short8 v; uint32_t u[4]; };

// ---------- prep: w1n[l][k][o] (o<32: W1a[o][k], o>=32: W1b[o-32][k]), w1c[l][d]=W1[d][64] ----------
__global__ __launch_bounds__(256) void k_prep(const float* __restrict__ w1,
                                              float* __restrict__ w1n,
                                              float* __restrict__ w1c) {
  int t = blockIdx.x * 256 + threadIdx.x;
  if (t < 4 * 2048) {
    int l = t >> 11, r = t & 2047, k = r >> 6, o = r & 63;
    w1n[t] = (o < 32) ? w1[l * 2080 + o * 65 + k]
                      : w1[l * 2080 + (o - 32) * 65 + (k + 32)];
  } else if (t < 4 * 2048 + 4 * 32) {
    int u = t - 4 * 2048;
    int l = u >> 5, d = u & 31;
    w1c[u] = w1[l * 2080 + d * 65 + 64];
  }
}

// ---------- h = x @ Wi^T + bi ----------
__global__ __launch_bounds__(256) void k_init(const float* __restrict__ x,
                                              const float* __restrict__ wi,
                                              const float* __restrict__ bi,
                                              float* __restrict__ h, int N) {
  int t = blockIdx.x * 256 + threadIdx.x;
  if (t >= N * 32) return;
  int n = t >> 5, d = t & 31;
  h[t] = fmaf(x[2 * n], wi[2 * d], fmaf(x[2 * n + 1], wi[2 * d + 1], bi[d]));
}

// Single pass: bucket edges by dst partition AND compute global per-node rank
// (fused histogram). Bucket record is 8B/edge:
//   b0 = (src << 14) | rank        (src < 2^17, rank < 2^14)
//   b1 = (d_local << 16) | ea_bf16 (d_local < pstep <= 2^14)
// CHUNK=1024 (4 edges/thread) -> 2x blocks vs round 16: more waves resident to
// hide the ~900cy random atomic RMW latency (occupancy was the limiter, 27%).
#define CHUNK 1024
__global__ __launch_bounds__(256) void k_bucket(const int* __restrict__ src,
                                                const int* __restrict__ dst,
                                                const float* __restrict__ ea,
                                                int* __restrict__ gcur,
                                                int* __restrict__ cnt,
                                                uint32_t* __restrict__ b0,
                                                uint32_t* __restrict__ b1,
                                                int E, int pstep, int cap) {
  __shared__ int lcnt[8], lbase[8];
  const int t = threadIdx.x;
  const int base = blockIdx.x * CHUNK;
  if (t < 8) lcnt[t] = 0;
  __syncthreads();
  int ps[4];
  uint32_t w0[4], w1[4];
#pragma unroll
  for (int j = 0; j < 4; j++) {
    int e = base + j * 256 + t;
    bool ok = e < E;
    int d = ok ? dst[e] : 0;
    int s = ok ? src[e] : 0;
    float eav = ok ? ea[e] : 0.f;
    int g = d / pstep;
    ps[j] = ok ? g : -1;
    if (ok) {
      int rank = atomicAdd(cnt + d, 1);            // global per-node rank + histogram
      w0[j] = ((uint32_t)s << 14) | (uint32_t)(rank & 16383);
      w1[j] = ((uint32_t)(d - g * pstep) << 16) | (uint32_t)f2bf(eav);
      atomicAdd(&lcnt[g], 1);
    }
  }
  __syncthreads();
  if (t < 8) lbase[t] = atomicAdd(&gcur[t], lcnt[t]);
  __syncthreads();
  if (t < 8) lcnt[t] = lbase[t];   // reuse as block-local cursor
  __syncthreads();
#pragma unroll
  for (int j = 0; j < 4; j++) {
    if (ps[j] >= 0) {
      int pos = atomicAdd(&lcnt[ps[j]], 1);
      if (pos < cap) {   // statistically impossible overflow guard
        size_t idx = (size_t)ps[j] * cap + pos;
        b0[idx] = w0[j];
        b1[idx] = w1[j];
      }
    }
  }
}

__global__ __launch_bounds__(256) void k_scan1(const int* __restrict__ in,
                                               int* __restrict__ out,
                                               int* __restrict__ bsum, int n) {
  __shared__ int sh[256];
  const int t = threadIdx.x;
  const int idx = blockIdx.x * 1024 + t * 4;
  int v[4];
#pragma unroll
  for (int j = 0; j < 4; j++) v[j] = (idx + j < n) ? in[idx + j] : 0;
  int tsum = v[0] + v[1] + v[2] + v[3];
  sh[t] = tsum;
  __syncthreads();
#pragma unroll
  for (int ofs = 1; ofs < 256; ofs <<= 1) {
    int x = (t >= ofs) ? sh[t - ofs] : 0;
    __syncthreads();
    sh[t] += x;
    __syncthreads();
  }
  int run = sh[t] - tsum;
  if (t == 255) bsum[blockIdx.x] = sh[255];
#pragma unroll
  for (int j = 0; j < 4; j++) {
    if (idx + j < n) out[idx + j] = run;
    run += v[j];
  }
}
__global__ __launch_bounds__(256) void k_scan2(int* __restrict__ bsum, int nb) {
  __shared__ int sh[256];
  const int t = threadIdx.x;
  int val = (t < nb) ? bsum[t] : 0;
  sh[t] = val;
  __syncthreads();
#pragma unroll
  for (int ofs = 1; ofs < 256; ofs <<= 1) {
    int x = (t >= ofs) ? sh[t - ofs] : 0;
    __syncthreads();
    sh[t] += x;
    __syncthreads();
  }
  if (t < nb) bsum[t] = sh[t] - val;
}
__global__ __launch_bounds__(256) void k_scan3(int* __restrict__ rowptr,
                                               const int* __restrict__ bsum, int n) {
  int t = blockIdx.x * 256 + threadIdx.x;
  if (t >= n) return;
  rowptr[t] = rowptr[t] + bsum[t >> 10];
}

// ---------- per-node factor (layer 0 only): one wave per node ----------
// (b1 dropped: column-constant bias cancels exactly through training-mode BN)
__global__ __launch_bounds__(256) void k_node(const float* __restrict__ h,
                                              const float* __restrict__ w1n,
                                              unsigned short* __restrict__ hAB, int N) {
  const int wid = (blockIdx.x * 256 + threadIdx.x) >> 6;
  const int lane = threadIdx.x & 63;
  if (wid >= N) return;
  const int n = __builtin_amdgcn_readfirstlane(wid);
  const float* hn = h + (size_t)n * 32;   // wave-uniform base -> s_load
  float acc = 0.f;
#pragma unroll
  for (int k = 0; k < 32; k++) acc = fmaf(hn[k], w1n[k * 64 + lane], acc);
  hAB[(size_t)n * 64 + lane] = f2bf(acc);
}

// ---------- pass A (4 lanes per edge): mpre[rowptr[d]+rank] = hA[d]+hB[src]+ea*w1c ----------
__global__ __launch_bounds__(256) void k_combine(
    const uint32_t* __restrict__ hAB, const uint32_t* __restrict__ b0,
    const uint32_t* __restrict__ b1, const int* __restrict__ gcur,
    const int* __restrict__ rowptr, const float* __restrict__ w1c,
    uint32_t* __restrict__ mpre, float* __restrict__ stats, int pstep, int cap) {
  const int t = threadIdx.x;
  const int r = t & 3;                    // sub-lane: channels [8r, 8r+8)
  float ssum[8], ssq[8];
#pragma unroll
  for (int q = 0; q < 8; q++) { ssum[q] = 0.f; ssq[q] = 0.f; }
  float wc[8];
#pragma unroll
  for (int j = 0; j < 8; j++) wc[j] = w1c[8 * r + j];

  const int gstride = (gridDim.x * blockDim.x) >> 2;
  const int eg0 = (blockIdx.x * blockDim.x + t) >> 2;
  for (int g = 0; g < 8; g++) {
    const int len = gcur[g];
    const size_t o = (size_t)g * cap;
    for (int i = eg0; i < len; i += gstride) {
      const uint32_t w0 = b0[o + i];      // 4 lanes same addr -> broadcast
      const uint32_t w1 = b1[o + i];
      const int vs = (int)(w0 >> 14);
      const int rank = (int)(w0 & 16383u);
      const int d = g * pstep + (int)(w1 >> 16);
      const float eav = bf2f((unsigned short)(w1 & 0xffffu));
      const int pos = rowptr[d] + rank;
      const uint4 av = *(const uint4*)(hAB + (size_t)d * 32 + r * 4);        // hA chans 8r..8r+7
      const uint4 bv = *(const uint4*)(hAB + (size_t)vs * 32 + 16 + r * 4);  // hB chans 8r..8r+7
      const uint32_t ad[4] = {av.x, av.y, av.z, av.w};
      const uint32_t bd[4] = {bv.x, bv.y, bv.z, bv.w};
      float m[8];
#pragma unroll
      for (int p = 0; p < 4; p++) {
        float a0 = __uint_as_float(ad[p] << 16), a1 = __uint_as_float(ad[p] & 0xffff0000u);
        float bb0 = __uint_as_float(bd[p] << 16), bb1 = __uint_as_float(bd[p] & 0xffff0000u);
        m[2 * p]     = a0 + fmaf(eav, wc[2 * p],     bb0);
        m[2 * p + 1] = a1 + fmaf(eav, wc[2 * p + 1], bb1);
      }
      uint4 out = make_uint4(pack2_bf16(m[0], m[1]), pack2_bf16(m[2], m[3]),
                             pack2_bf16(m[4], m[5]), pack2_bf16(m[6], m[7]));
      *(uint4*)(mpre + (size_t)pos * 16 + r * 4) = out;   // 4 lanes -> one full 64B line
#pragma unroll
      for (int q = 0; q < 8; q++) { ssum[q] += m[q]; ssq[q] = fmaf(m[q], m[q], ssq[q]); }
    }
  }
  // reduce over the 16 lanes sharing the same r (channel block)
#pragma unroll
  for (int q = 0; q < 8; q++) {
#pragma unroll
    for (int msk = 4; msk <= 32; msk <<= 1) {
      ssum[q] += __shfl_xor(ssum[q], msk, 64);
      ssq[q]  += __shfl_xor(ssq[q],  msk, 64);
    }
  }
  __shared__ float red[4][64];
  const int lane = t & 63, wv = t >> 6;
  if (lane < 4) {
#pragma unroll
    for (int j = 0; j < 8; j++) {
      red[wv][lane * 8 + j]      = ssum[j];
      red[wv][32 + lane * 8 + j] = ssq[j];
    }
  }
  __syncthreads();
  if (t < 64)
    stats[(size_t)blockIdx.x * 64 + t] = red[0][t] + red[1][t] + red[2][t] + red[3][t];
}

// ---------- finalize (parallel): block q reduces col q (sum) and q+32 (sumsq) ----------
__global__ __launch_bounds__(256) void k_finalize(const float* __restrict__ stats, int nblk, int E,
                                                  const float* __restrict__ g,
                                                  const float* __restrict__ bb,
                                                  float* __restrict__ ss) {
  const int q = blockIdx.x;
  const int t = threadIdx.x;
  double s0 = 0.0, s1 = 0.0;
  for (int i = t; i < nblk; i += 256) {
    s0 += (double)stats[(size_t)i * 64 + q];
    s1 += (double)stats[(size_t)i * 64 + 32 + q];
  }
  __shared__ double r0[256], r1[256];
  r0[t] = s0; r1[t] = s1;
  __syncthreads();
#pragma unroll
  for (int m = 128; m >= 1; m >>= 1) {
    if (t < m) { r0[t] += r0[t + m]; r1[t] += r1[t + m]; }
    __syncthreads();
  }
  if (t == 0) {
    double invE = 1.0 / (double)E;
    double mu = r0[0] * invE;
    double var = r1[0] * invE - mu * mu;
    if (var < 0.0) var = 0.0;
    double sc = (double)g[q] / sqrt(var + 1e-5);
    ss[q] = (float)sc;
    ss[32 + q] = (float)((double)bb[q] - mu * sc);
  }
}

// ---------- pass B (MFMA): m1 = relu(bn1(m_pre)); m_pre = m1 @ W2^T ; stats ----------
__global__ __launch_bounds__(256) void k_gemm2m(
    uint32_t* __restrict__ mpre, const float* __restrict__ ss,
    const float* __restrict__ w2, float* __restrict__ stats, int E) {
  const int lane = threadIdx.x & 63;
  const int wv = threadIdx.x >> 6;
  const int row = lane & 15;
  const int kb = (lane >> 4) * 8;
  const int G = E >> 4;
  const int gstart = blockIdx.x * 4 + wv;
  const int gstride = gridDim.x * 4;

  float sc[8], sh[8];
#pragma unroll
  for (int j = 0; j < 8; j++) { sc[j] = ss[kb + j]; sh[j] = ss[32 + kb + j]; }

  frag_u b0, b1;
#pragma unroll
  for (int p = 0; p < 4; p++) {
    const float* wp0 = w2 + (size_t)row * 32 + kb + 2 * p;
    const float* wp1 = w2 + (size_t)(row + 16) * 32 + kb + 2 * p;
    b0.u[p] = pack2_bf16(wp0[0], wp0[1]);
    b1.u[p] = pack2_bf16(wp1[0], wp1[1]);
  }

  float sum0 = 0.f, sq0 = 0.f, sum1 = 0.f, sq1 = 0.f;
  unsigned short* mp16 = (unsigned short*)mpre;

  for (int g = gstart; g < G; g += gstride) {
    const int e0 = g << 4;
    const uint4 raw = *(const uint4*)(mpre + (size_t)(e0 + row) * 16 + (lane >> 4) * 4);
    float m[8];
    m[0] = __uint_as_float(raw.x << 16); m[1] = __uint_as_float(raw.x & 0xffff0000u);
    m[2] = __uint_as_float(raw.y << 16); m[3] = __uint_as_float(raw.y & 0xffff0000u);
    m[4] = __uint_as_float(raw.z << 16); m[5] = __uint_as_float(raw.z & 0xffff0000u);
    m[6] = __uint_as_float(raw.w << 16); m[7] = __uint_as_float(raw.w & 0xffff0000u);
    frag_u a;
#pragma unroll
    for (int p = 0; p < 4; p++) {
      float x0 = fmaxf(fmaf(m[2 * p],     sc[2 * p],     sh[2 * p]),     0.f);
      float x1 = fmaxf(fmaf(m[2 * p + 1], sc[2 * p + 1], sh[2 * p + 1]), 0.f);
      a.u[p] = pack2_bf16(x0, x1);
    }
    f32x4 z = {0.f, 0.f, 0.f, 0.f};
    f32x4 acc0 = __builtin_amdgcn_mfma_f32_16x16x32_bf16(a.v, b0.v, z, 0, 0, 0);
    f32x4 acc1 = __builtin_amdgcn_mfma_f32_16x16x32_bf16(a.v, b1.v, z, 0, 0, 0);
#pragma unroll
    for (int r = 0; r < 4; r++) {
      sum0 += acc0[r]; sq0 = fmaf(acc0[r], acc0[r], sq0);
      sum1 += acc1[r]; sq1 = fmaf(acc1[r], acc1[r], sq1);
      const size_t base = (size_t)(e0 + (lane >> 4) * 4 + r) * 32;
      mp16[base + row]      = f2bf(acc0[r]);
      mp16[base + row + 16] = f2bf(acc1[r]);
    }
  }

  sum0 += __shfl_xor(sum0, 16); sum0 += __shfl_xor(sum0, 32);
  sq0  += __shfl_xor(sq0, 16);  sq0  += __shfl_xor(sq0, 32);
  sum1 += __shfl_xor(sum1, 16); sum1 += __shfl_xor(sum1, 32);
  sq1  += __shfl_xor(sq1, 16);  sq1  += __shfl_xor(sq1, 32);
  __shared__ float red[4][64];
  if (lane < 16) {
    red[wv][row] = sum0;      red[wv][16 + row] = sum1;
    red[wv][32 + row] = sq0;  red[wv][48 + row] = sq1;
  }
  __syncthreads();
  if (threadIdx.x < 64) {
    int q = threadIdx.x;
    stats[(size_t)blockIdx.x * 64 + q] = red[0][q] + red[1][q] + red[2][q] + red[3][q];
  }
}

// ---------- pass C fused: h[n] += agg; hAB[n] = (h[n] @ W1next) (unless last) ----------
// One WAVE per node. Lanes: d = lane&31, half = lane>>5. Even/odd edges split
// across halves, merged via shfl_xor(32). Node transform via 32 shfl broadcasts.
__global__ __launch_bounds__(256) void k_aggnode(
    const unsigned short* __restrict__ mp16, const int* __restrict__ rowptr,
    const int* __restrict__ cnt, const float* __restrict__ ss,
    float* __restrict__ h, const float* __restrict__ w1n,
    unsigned short* __restrict__ hAB, int N, int last) {
  const int wid = (blockIdx.x * 256 + threadIdx.x) >> 6;
  const int lane = threadIdx.x & 63;
  if (wid >= N) return;
  const int n = __builtin_amdgcn_readfirstlane(wid);
  const int d = lane & 31, half = lane >> 5;
  const int start = rowptr[n];
  const int deg = cnt[n];
  const float scv = ss[d], shv = ss[32 + d];
  const unsigned short* p = mp16 + (size_t)start * 32 + d;
  float acc = 0.f;
  for (int j = half; j < deg; j += 2) {
    float x = bf2f(p[(size_t)j * 32]);
    acc += fmaxf(fmaf(x, scv, shv), 0.f);
  }
  acc += __shfl_xor(acc, 32, 64);
  const float hnew = h[(size_t)n * 32 + d] + acc;
  if (lane < 32) h[(size_t)n * 32 + lane] = hnew;
  if (last) return;
  float acc2 = 0.f;
#pragma unroll
  for (int k = 0; k < 32; k++)
    acc2 = fmaf(__shfl(hnew, k, 64), w1n[k * 64 + lane], acc2);
  hAB[(size_t)n * 64 + lane] = f2bf(acc2);
}

// ---------- readout ----------
__global__ __launch_bounds__(256) void k_initseg(unsigned* __restrict__ segmax,
                                                 float* __restrict__ segsum) {
  int t = blockIdx.x * 256 + threadIdx.x;
  if (t < NGRAPH) { segmax[t] = 0u; segsum[t] = 0.f; }
}

__global__ __launch_bounds__(256) void k_logits(
    const float* __restrict__ h, const int* __restrict__ cand, const int* __restrict__ batch,
    const float* __restrict__ wout, const float* __restrict__ bout,
    float* __restrict__ logits, int* __restrict__ seg, unsigned* __restrict__ segmax, int C) {
  int t = blockIdx.x * 256 + threadIdx.x;
  if (t >= C) return;
  int node = cand[t];
  const float4* hp = (const float4*)(h + (size_t)node * 32);
  float acc = bout[0];
#pragma unroll
  for (int kc = 0; kc < 8; kc++) {
    float4 v = hp[kc];
    acc = fmaf(v.x, wout[kc * 4 + 0], acc);
    acc = fmaf(v.y, wout[kc * 4 + 1], acc);
    acc = fmaf(v.z, wout[kc * 4 + 2], acc);
    acc = fmaf(v.w, wout[kc * 4 + 3], acc);
  }
  logits[t] = acc;
  int s = batch[node];
  seg[t] = s;
  unsigned o = __float_as_uint(acc);
  o ^= (o >> 31) ? 0xFFFFFFFFu : 0x80000000u;
  atomicMax(segmax + s, o);
}

static __device__ __forceinline__ float o2f(unsigned o) {
  o ^= (o & 0x80000000u) ? 0x80000000u : 0xFFFFFFFFu;
  return __uint_as_float(o);
}

__global__ __launch_bounds__(256) void k_expsum(const float* __restrict__ logits,
                                                const int* __restrict__ seg,
                                                const unsigned* __restrict__ segmax,
                                                float* __restrict__ segsum, int C) {
  int t = blockIdx.x * 256 + threadIdx.x;
  if (t >= C) return;
  int s = seg[t];
  float mx = o2f(segmax[s]);
  atomicAdd(segsum + s, expf(logits[t] - mx));
}

__global__ __launch_bounds__(256) void k_out(const float* __restrict__ logits,
                                             const int* __restrict__ seg,
                                             const unsigned* __restrict__ segmax,
                                             const float* __restrict__ segsum,
                                             float* __restrict__ out, int C) {
  int t = blockIdx.x * 256 + threadIdx.x;
  if (t >= C) return;
  int s = seg[t];
  out[t] = logits[t] - (o2f(segmax[s]) + logf(segsum[s]));
}

// ---------- launch ----------
extern "C" void kernel_launch(void* const* d_in, const int* in_sizes, int n_in,
                              void* d_out, int out_size, void* d_ws, size_t ws_size,
                              hipStream_t stream) {
  const float* x     = (const float*)d_in[0];
  const int*   eidx  = (const int*)d_in[1];
  const float* eattr = (const float*)d_in[2];
  const int*   cand  = (const int*)d_in[3];
  const int*   batch = (const int*)d_in[4];
  const float* wi    = (const float*)d_in[5];
  const float* bi    = (const float*)d_in[6];
  const float* w1    = (const float*)d_in[7];
  const float* g1    = (const float*)d_in[9];
  const float* bb1   = (const float*)d_in[10];
  const float* w2    = (const float*)d_in[11];
  const float* g2    = (const float*)d_in[13];
  const float* bb2   = (const float*)d_in[14];
  const float* wout  = (const float*)d_in[15];
  const float* bout  = (const float*)d_in[16];
  // b1 (d_in[8]) and b2 (d_in[12]) cancel exactly through training-mode BN.

  const int N = in_sizes[4];
  const int E = in_sizes[2];
  const int C = in_sizes[3];
  const int* src  = eidx;
  const int* dstp = eidx + E;

  // workspace carve (~144 MB)
  char* ws = (char*)d_ws;
  size_t off = 0;
  auto carve = [&](size_t bytes) {
    void* p = ws + off;
    off = (off + bytes + 255) & ~(size_t)255;
    return p;
  };
  const int NBLK = 1024;
  const int pstep = (N + 7) / 8;
  const int cap = E / 8 + 8192;   // Binomial(E,1/8) sigma~420 -> ~19 sigma margin
  uint32_t* mpre   = (uint32_t*)carve((size_t)E * 64);        // [E][32] bf16 (CSR slot order)
  float*    h      = (float*)carve((size_t)N * 32 * 4);       // [N][32] f32
  uint32_t* hAB    = (uint32_t*)carve((size_t)N * 128);       // [N][64] bf16 (hA|hB)
  float*    w1n    = (float*)carve(4 * 2048 * 4);             // [l][k][o]
  float*    w1c    = (float*)carve(4 * 32 * 4);               // [l][d]
  float*    ss     = (float*)carve(64 * 4);
  float*    stats  = (float*)carve((size_t)NBLK * 64 * 4);
  int*      cnt    = (int*)carve((size_t)N * 4);
  int*      rowptr = (int*)carve((size_t)N * 4);
  int*      bsum   = (int*)carve(256 * 4);
  int*      gcur   = (int*)carve(8 * 4);                      // bucket cursors
  uint32_t* b0     = (uint32_t*)carve((size_t)8 * cap * 4);   // (src<<14)|rank
  uint32_t* b1buf  = (uint32_t*)carve((size_t)8 * cap * 4);   // (d_local<<16)|ea_bf16
  float*    logits = (float*)carve((size_t)C * 4);
  int*      seg    = (int*)carve((size_t)C * 4);
  unsigned* segmax = (unsigned*)carve(NGRAPH * 4);
  float*    segsum = (float*)carve(NGRAPH * 4);
  (void)ws_size; (void)n_in; (void)out_size;

  // CSR metadata: one fused bucket+histogram+rank pass, then scan
  const int nb1 = (N + 1023) / 1024;
  hipMemsetAsync(cnt, 0, (size_t)N * 4, stream);
  hipMemsetAsync(gcur, 0, 8 * 4, stream);
  k_bucket<<<(E + CHUNK - 1) / CHUNK, 256, 0, stream>>>(src, dstp, eattr, gcur, cnt,
                                                        b0, b1buf, E, pstep, cap);
  k_scan1<<<nb1, 256, 0, stream>>>(cnt, rowptr, bsum, N);
  k_scan2<<<1, 256, 0, stream>>>(bsum, nb1);
  k_scan3<<<(N + 255) / 256, 256, 0, stream>>>(rowptr, bsum, N);

  k_prep<<<33, 256, 0, stream>>>(w1, w1n, w1c);
  k_init<<<(N * 32 + 255) / 256, 256, 0, stream>>>(x, wi, bi, h, N);
  k_node<<<(N * 64 + 255) / 256, 256, 0, stream>>>(h, w1n, (unsigned short*)hAB, N);

  for (int l = 0; l < 4; l++) {
    k_combine<<<NBLK, 256, 0, stream>>>(hAB, b0, b1buf, gcur, rowptr, w1c + l * 32,
                                        mpre, stats, pstep, cap);
    k_finalize<<<32, 256, 0, stream>>>(stats, NBLK, E, g1 + l * 32, bb1 + l * 32, ss);
    k_gemm2m<<<NBLK, 256, 0, stream>>>(mpre, ss, w2 + l * 1024, stats, E);
    k_finalize<<<32, 256, 0, stream>>>(stats, NBLK, E, g2 + l * 32, bb2 + l * 32, ss);
    k_aggnode<<<(N * 64 + 255) / 256, 256, 0, stream>>>(
        (const unsigned short*)mpre, rowptr, cnt, ss, h,
        w1n + (l + 1 < 4 ? (l + 1) * 2048 : 0), (unsigned short*)hAB, N, l == 3);
  }

  k_initseg<<<(NGRAPH + 255) / 256, 256, 0, stream>>>(segmax, segsum);
  k_logits<<<(C + 255) / 256, 256, 0, stream>>>(h, cand, batch, wout, bout,
                                                logits, seg, segmax, C);
  k_expsum<<<(C + 255) / 256, 256, 0, stream>>>(logits, seg, segmax, segsum, C);
  k_out<<<(C + 255) / 256, 256, 0, stream>>>(logits, seg, segmax, segsum, (float*)d_out, C);
}

// Round 18
// 785.580 us; speedup vs baseline: 1.0523x; 1.0523x over previous
//
#include <hip/hip_runtime.h>
#include <stdint.h>

#define NGRAPH 1000

typedef __attribute__((ext_vector_type(8))) short short8;
typedef __attribute__((ext_vector_type(4))) float f32x4;

// ---------- helpers ----------
static __device__ __forceinline__ uint32_t pack2_bf16(float a, float b) {
  uint32_t ua = __float_as_uint(a), ub = __float_as_uint(b);
  ua = (ua + 0x7fffu + ((ua >> 16) & 1u)) >> 16;   // RNE
  ub = (ub + 0x7fffu + ((ub >> 16) & 1u)) >> 16;
  return ua | (ub << 16);
}
static __device__ __forceinline__ unsigned short f2bf(float x) {
  uint32_t u = __float_as_uint(x);
  u = (u + 0x7fffu + ((u >> 16) & 1u)) >> 16;
  return (unsigned short)u;
}
static __device__ __forceinline__ float bf2f(unsigned short u) {
  return __uint_as_float(((uint32_t)u) << 16);
}
union frag_u { short8 v; uint32_t u[4]; };

// ---------- prep: w1n[l][k][o] (o<32: W1a[o][k], o>=32: W1b[o-32][k]), w1c[l][d]=W1[d][64] ----------
__global__ __launch_bounds__(256) void k_prep(const float* __restrict__ w1,
                                              float* __restrict__ w1n,
                                              float* __restrict__ w1c) {
  int t = blockIdx.x * 256 + threadIdx.x;
  if (t < 4 * 2048) {
    int l = t >> 11, r = t & 2047, k = r >> 6, o = r & 63;
    w1n[t] = (o < 32) ? w1[l * 2080 + o * 65 + k]
                      : w1[l * 2080 + (o - 32) * 65 + (k + 32)];
  } else if (t < 4 * 2048 + 4 * 32) {
    int u = t - 4 * 2048;
    int l = u >> 5, d = u & 31;
    w1c[u] = w1[l * 2080 + d * 65 + 64];
  }
}

// ---------- CSR metadata build ----------
__global__ __launch_bounds__(256) void k_zero32(int* __restrict__ p, int n) {
  int t = blockIdx.x * 256 + threadIdx.x;
  if (t < n) p[t] = 0;
}

// Single pass: bucket edges by dst partition AND compute global per-node rank
// (fused histogram). Bucket record is 8B/edge:
//   b0 = (src << 14) | rank        (src < 2^17, rank < 2^14)
//   b1 = (d_local << 16) | ea_bf16 (d_local < pstep <= 2^14)
// NOTE (r17 evidence): k_bucket is bound by device-scope atomic RMW throughput
// (~20 G/s), NOT latency — occupancy 27%->55% left dur unchanged. CHUNK=2048.
#define CHUNK 2048
__global__ __launch_bounds__(256) void k_bucket(const int* __restrict__ src,
                                                const int* __restrict__ dst,
                                                const float* __restrict__ ea,
                                                int* __restrict__ gcur,
                                                int* __restrict__ cnt,
                                                uint32_t* __restrict__ b0,
                                                uint32_t* __restrict__ b1,
                                                int E, int pstep, int cap) {
  __shared__ int lcnt[8], lbase[8];
  const int t = threadIdx.x;
  const int base = blockIdx.x * CHUNK;
  if (t < 8) lcnt[t] = 0;
  __syncthreads();
  int ps[8];
  uint32_t w0[8], w1[8];
#pragma unroll
  for (int j = 0; j < 8; j++) {
    int e = base + j * 256 + t;
    bool ok = e < E;
    int d = ok ? dst[e] : 0;
    int s = ok ? src[e] : 0;
    float eav = ok ? ea[e] : 0.f;
    int g = d / pstep;
    ps[j] = ok ? g : -1;
    if (ok) {
      int rank = atomicAdd(cnt + d, 1);            // global per-node rank + histogram
      w0[j] = ((uint32_t)s << 14) | (uint32_t)(rank & 16383);
      w1[j] = ((uint32_t)(d - g * pstep) << 16) | (uint32_t)f2bf(eav);
      atomicAdd(&lcnt[g], 1);
    }
  }
  __syncthreads();
  if (t < 8) lbase[t] = atomicAdd(&gcur[t], lcnt[t]);
  __syncthreads();
  if (t < 8) lcnt[t] = lbase[t];   // reuse as block-local cursor
  __syncthreads();
#pragma unroll
  for (int j = 0; j < 8; j++) {
    if (ps[j] >= 0) {
      int pos = atomicAdd(&lcnt[ps[j]], 1);
      if (pos < cap) {   // statistically impossible overflow guard
        size_t idx = (size_t)ps[j] * cap + pos;
        b0[idx] = w0[j];
        b1[idx] = w1[j];
      }
    }
  }
}

__global__ __launch_bounds__(256) void k_scan1(const int* __restrict__ in,
                                               int* __restrict__ out,
                                               int* __restrict__ bsum, int n) {
  __shared__ int sh[256];
  const int t = threadIdx.x;
  const int idx = blockIdx.x * 1024 + t * 4;
  int v[4];
#pragma unroll
  for (int j = 0; j < 4; j++) v[j] = (idx + j < n) ? in[idx + j] : 0;
  int tsum = v[0] + v[1] + v[2] + v[3];
  sh[t] = tsum;
  __syncthreads();
#pragma unroll
  for (int ofs = 1; ofs < 256; ofs <<= 1) {
    int x = (t >= ofs) ? sh[t - ofs] : 0;
    __syncthreads();
    sh[t] += x;
    __syncthreads();
  }
  int run = sh[t] - tsum;
  if (t == 255) bsum[blockIdx.x] = sh[255];
#pragma unroll
  for (int j = 0; j < 4; j++) {
    if (idx + j < n) out[idx + j] = run;
    run += v[j];
  }
}
__global__ __launch_bounds__(256) void k_scan2(int* __restrict__ bsum, int nb) {
  __shared__ int sh[256];
  const int t = threadIdx.x;
  int val = (t < nb) ? bsum[t] : 0;
  sh[t] = val;
  __syncthreads();
#pragma unroll
  for (int ofs = 1; ofs < 256; ofs <<= 1) {
    int x = (t >= ofs) ? sh[t - ofs] : 0;
    __syncthreads();
    sh[t] += x;
    __syncthreads();
  }
  if (t < nb) bsum[t] = sh[t] - val;
}
__global__ __launch_bounds__(256) void k_scan3(int* __restrict__ rowptr,
                                               const int* __restrict__ bsum, int n) {
  int t = blockIdx.x * 256 + threadIdx.x;
  if (t >= n) return;
  rowptr[t] = rowptr[t] + bsum[t >> 10];
}

// ---------- fused init+node (layer 0): one wave per node ----------
// lane<32 computes h[n][lane] = x[n]@Wi^T+bi in-register; broadcast via shfl
// feeds the W1 transform. Saves the h round-trip k_init->k_node had.
__global__ __launch_bounds__(256) void k_initnode(const float* __restrict__ x,
                                                  const float* __restrict__ wi,
                                                  const float* __restrict__ bi,
                                                  const float* __restrict__ w1n,
                                                  float* __restrict__ h,
                                                  unsigned short* __restrict__ hAB, int N) {
  const int wid = (blockIdx.x * 256 + threadIdx.x) >> 6;
  const int lane = threadIdx.x & 63;
  if (wid >= N) return;
  const int n = __builtin_amdgcn_readfirstlane(wid);
  const int d = lane & 31;
  const float x0 = x[2 * n], x1 = x[2 * n + 1];   // wave-uniform -> s_load
  const float hval = fmaf(x0, wi[2 * d], fmaf(x1, wi[2 * d + 1], bi[d]));
  if (lane < 32) h[(size_t)n * 32 + lane] = hval;
  float acc = 0.f;
#pragma unroll
  for (int k = 0; k < 32; k++)
    acc = fmaf(__shfl(hval, k, 64), w1n[k * 64 + lane], acc);
  hAB[(size_t)n * 64 + lane] = f2bf(acc);
}

// ---------- per-node factor (layers 1..3): one wave per node ----------
// (b1 dropped: column-constant bias cancels exactly through training-mode BN)
__global__ __launch_bounds__(256) void k_node(const float* __restrict__ h,
                                              const float* __restrict__ w1n,
                                              unsigned short* __restrict__ hAB, int N) {
  const int wid = (blockIdx.x * 256 + threadIdx.x) >> 6;
  const int lane = threadIdx.x & 63;
  if (wid >= N) return;
  const int n = __builtin_amdgcn_readfirstlane(wid);
  const float* hn = h + (size_t)n * 32;   // wave-uniform base -> s_load
  float acc = 0.f;
#pragma unroll
  for (int k = 0; k < 32; k++) acc = fmaf(hn[k], w1n[k * 64 + lane], acc);
  hAB[(size_t)n * 64 + lane] = f2bf(acc);
}

// ---------- pass A (4 lanes per edge): mpre[rowptr[d]+rank] = hA[d]+hB[src]+ea*w1c ----------
__global__ __launch_bounds__(256) void k_combine(
    const uint32_t* __restrict__ hAB, const uint32_t* __restrict__ b0,
    const uint32_t* __restrict__ b1, const int* __restrict__ gcur,
    const int* __restrict__ rowptr, const float* __restrict__ w1c,
    uint32_t* __restrict__ mpre, float* __restrict__ stats, int pstep, int cap) {
  const int t = threadIdx.x;
  const int r = t & 3;                    // sub-lane: channels [8r, 8r+8)
  float ssum[8], ssq[8];
#pragma unroll
  for (int q = 0; q < 8; q++) { ssum[q] = 0.f; ssq[q] = 0.f; }
  float wc[8];
#pragma unroll
  for (int j = 0; j < 8; j++) wc[j] = w1c[8 * r + j];

  const int gstride = (gridDim.x * blockDim.x) >> 2;
  const int eg0 = (blockIdx.x * blockDim.x + t) >> 2;
  for (int g = 0; g < 8; g++) {
    const int len = gcur[g];
    const size_t o = (size_t)g * cap;
    for (int i = eg0; i < len; i += gstride) {
      const uint32_t w0 = b0[o + i];      // 4 lanes same addr -> broadcast
      const uint32_t w1 = b1[o + i];
      const int vs = (int)(w0 >> 14);
      const int rank = (int)(w0 & 16383u);
      const int d = g * pstep + (int)(w1 >> 16);
      const float eav = bf2f((unsigned short)(w1 & 0xffffu));
      const int pos = rowptr[d] + rank;
      const uint4 av = *(const uint4*)(hAB + (size_t)d * 32 + r * 4);        // hA chans 8r..8r+7
      const uint4 bv = *(const uint4*)(hAB + (size_t)vs * 32 + 16 + r * 4);  // hB chans 8r..8r+7
      const uint32_t ad[4] = {av.x, av.y, av.z, av.w};
      const uint32_t bd[4] = {bv.x, bv.y, bv.z, bv.w};
      float m[8];
#pragma unroll
      for (int p = 0; p < 4; p++) {
        float a0 = __uint_as_float(ad[p] << 16), a1 = __uint_as_float(ad[p] & 0xffff0000u);
        float bb0 = __uint_as_float(bd[p] << 16), bb1 = __uint_as_float(bd[p] & 0xffff0000u);
        m[2 * p]     = a0 + fmaf(eav, wc[2 * p],     bb0);
        m[2 * p + 1] = a1 + fmaf(eav, wc[2 * p + 1], bb1);
      }
      uint4 out = make_uint4(pack2_bf16(m[0], m[1]), pack2_bf16(m[2], m[3]),
                             pack2_bf16(m[4], m[5]), pack2_bf16(m[6], m[7]));
      *(uint4*)(mpre + (size_t)pos * 16 + r * 4) = out;   // 4 lanes -> one full 64B line
#pragma unroll
      for (int q = 0; q < 8; q++) { ssum[q] += m[q]; ssq[q] = fmaf(m[q], m[q], ssq[q]); }
    }
  }
  // reduce over the 16 lanes sharing the same r (channel block)
#pragma unroll
  for (int q = 0; q < 8; q++) {
#pragma unroll
    for (int msk = 4; msk <= 32; msk <<= 1) {
      ssum[q] += __shfl_xor(ssum[q], msk, 64);
      ssq[q]  += __shfl_xor(ssq[q],  msk, 64);
    }
  }
  __shared__ float red[4][64];
  const int lane = t & 63, wv = t >> 6;
  if (lane < 4) {
#pragma unroll
    for (int j = 0; j < 8; j++) {
      red[wv][lane * 8 + j]      = ssum[j];
      red[wv][32 + lane * 8 + j] = ssq[j];
    }
  }
  __syncthreads();
  if (t < 64)
    stats[(size_t)blockIdx.x * 64 + t] = red[0][t] + red[1][t] + red[2][t] + red[3][t];
}

// ---------- finalize (parallel): block q reduces col q (sum) and q+32 (sumsq) ----------
__global__ __launch_bounds__(256) void k_finalize(const float* __restrict__ stats, int nblk, int E,
                                                  const float* __restrict__ g,
                                                  const float* __restrict__ bb,
                                                  float* __restrict__ ss) {
  const int q = blockIdx.x;
  const int t = threadIdx.x;
  double s0 = 0.0, s1 = 0.0;
  for (int i = t; i < nblk; i += 256) {
    s0 += (double)stats[(size_t)i * 64 + q];
    s1 += (double)stats[(size_t)i * 64 + 32 + q];
  }
  __shared__ double r0[256], r1[256];
  r0[t] = s0; r1[t] = s1;
  __syncthreads();
#pragma unroll
  for (int m = 128; m >= 1; m >>= 1) {
    if (t < m) { r0[t] += r0[t + m]; r1[t] += r1[t + m]; }
    __syncthreads();
  }
  if (t == 0) {
    double invE = 1.0 / (double)E;
    double mu = r0[0] * invE;
    double var = r1[0] * invE - mu * mu;
    if (var < 0.0) var = 0.0;
    double sc = (double)g[q] / sqrt(var + 1e-5);
    ss[q] = (float)sc;
    ss[32 + q] = (float)((double)bb[q] - mu * sc);
  }
}

// ---------- pass B (MFMA): m1 = relu(bn1(m_pre)); m_pre = m1 @ W2^T ; stats ----------
__global__ __launch_bounds__(256) void k_gemm2m(
    uint32_t* __restrict__ mpre, const float* __restrict__ ss,
    const float* __restrict__ w2, float* __restrict__ stats, int E) {
  const int lane = threadIdx.x & 63;
  const int wv = threadIdx.x >> 6;
  const int row = lane & 15;
  const int kb = (lane >> 4) * 8;
  const int G = E >> 4;
  const int gstart = blockIdx.x * 4 + wv;
  const int gstride = gridDim.x * 4;

  float sc[8], sh[8];
#pragma unroll
  for (int j = 0; j < 8; j++) { sc[j] = ss[kb + j]; sh[j] = ss[32 + kb + j]; }

  frag_u b0, b1;
#pragma unroll
  for (int p = 0; p < 4; p++) {
    const float* wp0 = w2 + (size_t)row * 32 + kb + 2 * p;
    const float* wp1 = w2 + (size_t)(row + 16) * 32 + kb + 2 * p;
    b0.u[p] = pack2_bf16(wp0[0], wp0[1]);
    b1.u[p] = pack2_bf16(wp1[0], wp1[1]);
  }

  float sum0 = 0.f, sq0 = 0.f, sum1 = 0.f, sq1 = 0.f;
  unsigned short* mp16 = (unsigned short*)mpre;

  for (int g = gstart; g < G; g += gstride) {
    const int e0 = g << 4;
    const uint4 raw = *(const uint4*)(mpre + (size_t)(e0 + row) * 16 + (lane >> 4) * 4);
    float m[8];
    m[0] = __uint_as_float(raw.x << 16); m[1] = __uint_as_float(raw.x & 0xffff0000u);
    m[2] = __uint_as_float(raw.y << 16); m[3] = __uint_as_float(raw.y & 0xffff0000u);
    m[4] = __uint_as_float(raw.z << 16); m[5] = __uint_as_float(raw.z & 0xffff0000u);
    m[6] = __uint_as_float(raw.w << 16); m[7] = __uint_as_float(raw.w & 0xffff0000u);
    frag_u a;
#pragma unroll
    for (int p = 0; p < 4; p++) {
      float x0 = fmaxf(fmaf(m[2 * p],     sc[2 * p],     sh[2 * p]),     0.f);
      float x1 = fmaxf(fmaf(m[2 * p + 1], sc[2 * p + 1], sh[2 * p + 1]), 0.f);
      a.u[p] = pack2_bf16(x0, x1);
    }
    f32x4 z = {0.f, 0.f, 0.f, 0.f};
    f32x4 acc0 = __builtin_amdgcn_mfma_f32_16x16x32_bf16(a.v, b0.v, z, 0, 0, 0);
    f32x4 acc1 = __builtin_amdgcn_mfma_f32_16x16x32_bf16(a.v, b1.v, z, 0, 0, 0);
#pragma unroll
    for (int r = 0; r < 4; r++) {
      sum0 += acc0[r]; sq0 = fmaf(acc0[r], acc0[r], sq0);
      sum1 += acc1[r]; sq1 = fmaf(acc1[r], acc1[r], sq1);
      const size_t base = (size_t)(e0 + (lane >> 4) * 4 + r) * 32;
      mp16[base + row]      = f2bf(acc0[r]);
      mp16[base + row + 16] = f2bf(acc1[r]);
    }
  }

  sum0 += __shfl_xor(sum0, 16); sum0 += __shfl_xor(sum0, 32);
  sq0  += __shfl_xor(sq0, 16);  sq0  += __shfl_xor(sq0, 32);
  sum1 += __shfl_xor(sum1, 16); sum1 += __shfl_xor(sum1, 32);
  sq1  += __shfl_xor(sq1, 16);  sq1  += __shfl_xor(sq1, 32);
  __shared__ float red[4][64];
  if (lane < 16) {
    red[wv][row] = sum0;      red[wv][16 + row] = sum1;
    red[wv][32 + row] = sq0;  red[wv][48 + row] = sq1;
  }
  __syncthreads();
  if (threadIdx.x < 64) {
    int q = threadIdx.x;
    stats[(size_t)blockIdx.x * 64 + q] = red[0][q] + red[1][q] + red[2][q] + red[3][q];
  }
}

// ---------- pass C (gather): h[n] += sum over contiguous CSR slots of relu(bn2(mpre)) ----------
__global__ __launch_bounds__(256) void k_agg(
    const unsigned short* __restrict__ mp16, const int* __restrict__ rowptr,
    const int* __restrict__ cnt, const float* __restrict__ ss,
    float* __restrict__ h, int N) {
  const int n = blockIdx.x * 8 + (threadIdx.x >> 5);
  if (n >= N) return;
  const int d = threadIdx.x & 31;
  const int start = rowptr[n];
  const int deg = cnt[n];
  const float sc = ss[d], sh = ss[32 + d];
  const unsigned short* p = mp16 + (size_t)start * 32 + d;
  float acc = 0.f;
  int j = 0;
  for (; j + 2 <= deg; j += 2) {
    float x0 = bf2f(p[(size_t)j * 32]);
    float x1 = bf2f(p[(size_t)(j + 1) * 32]);
    acc += fmaxf(fmaf(x0, sc, sh), 0.f);
    acc += fmaxf(fmaf(x1, sc, sh), 0.f);
  }
  if (j < deg) {
    float x0 = bf2f(p[(size_t)j * 32]);
    acc += fmaxf(fmaf(x0, sc, sh), 0.f);
  }
  h[(size_t)n * 32 + d] += acc;
}

// ---------- readout ----------
__global__ __launch_bounds__(256) void k_initseg(unsigned* __restrict__ segmax,
                                                 float* __restrict__ segsum) {
  int t = blockIdx.x * 256 + threadIdx.x;
  if (t < NGRAPH) { segmax[t] = 0u; segsum[t] = 0.f; }
}

__global__ __launch_bounds__(256) void k_logits(
    const float* __restrict__ h, const int* __restrict__ cand, const int* __restrict__ batch,
    const float* __restrict__ wout, const float* __restrict__ bout,
    float* __restrict__ logits, int* __restrict__ seg, unsigned* __restrict__ segmax, int C) {
  int t = blockIdx.x * 256 + threadIdx.x;
  if (t >= C) return;
  int node = cand[t];
  const float4* hp = (const float4*)(h + (size_t)node * 32);
  float acc = bout[0];
#pragma unroll
  for (int kc = 0; kc < 8; kc++) {
    float4 v = hp[kc];
    acc = fmaf(v.x, wout[kc * 4 + 0], acc);
    acc = fmaf(v.y, wout[kc * 4 + 1], acc);
    acc = fmaf(v.z, wout[kc * 4 + 2], acc);
    acc = fmaf(v.w, wout[kc * 4 + 3], acc);
  }
  logits[t] = acc;
  int s = batch[node];
  seg[t] = s;
  unsigned o = __float_as_uint(acc);
  o ^= (o >> 31) ? 0xFFFFFFFFu : 0x80000000u;
  atomicMax(segmax + s, o);
}

static __device__ __forceinline__ float o2f(unsigned o) {
  o ^= (o & 0x80000000u) ? 0x80000000u : 0xFFFFFFFFu;
  return __uint_as_float(o);
}

__global__ __launch_bounds__(256) void k_expsum(const float* __restrict__ logits,
                                                const int* __restrict__ seg,
                                                const unsigned* __restrict__ segmax,
                                                float* __restrict__ segsum, int C) {
  int t = blockIdx.x * 256 + threadIdx.x;
  if (t >= C) return;
  int s = seg[t];
  float mx = o2f(segmax[s]);
  atomicAdd(segsum + s, expf(logits[t] - mx));
}

__global__ __launch_bounds__(256) void k_out(const float* __restrict__ logits,
                                             const int* __restrict__ seg,
                                             const unsigned* __restrict__ segmax,
                                             const float* __restrict__ segsum,
                                             float* __restrict__ out, int C) {
  int t = blockIdx.x * 256 + threadIdx.x;
  if (t >= C) return;
  int s = seg[t];
  out[t] = logits[t] - (o2f(segmax[s]) + logf(segsum[s]));
}

// ---------- launch ----------
extern "C" void kernel_launch(void* const* d_in, const int* in_sizes, int n_in,
                              void* d_out, int out_size, void* d_ws, size_t ws_size,
                              hipStream_t stream) {
  const float* x     = (const float*)d_in[0];
  const int*   eidx  = (const int*)d_in[1];
  const float* eattr = (const float*)d_in[2];
  const int*   cand  = (const int*)d_in[3];
  const int*   batch = (const int*)d_in[4];
  const float* wi    = (const float*)d_in[5];
  const float* bi    = (const float*)d_in[6];
  const float* w1    = (const float*)d_in[7];
  const float* g1    = (const float*)d_in[9];
  const float* bb1   = (const float*)d_in[10];
  const float* w2    = (const float*)d_in[11];
  const float* g2    = (const float*)d_in[13];
  const float* bb2   = (const float*)d_in[14];
  const float* wout  = (const float*)d_in[15];
  const float* bout  = (const float*)d_in[16];
  // b1 (d_in[8]) and b2 (d_in[12]) cancel exactly through training-mode BN.

  const int N = in_sizes[4];
  const int E = in_sizes[2];
  const int C = in_sizes[3];
  const int* src  = eidx;
  const int* dstp = eidx + E;

  // workspace carve (~144 MB)
  char* ws = (char*)d_ws;
  size_t off = 0;
  auto carve = [&](size_t bytes) {
    void* p = ws + off;
    off = (off + bytes + 255) & ~(size_t)255;
    return p;
  };
  const int NBLK = 1024;
  const int pstep = (N + 7) / 8;
  const int cap = E / 8 + 8192;   // Binomial(E,1/8) sigma~420 -> ~19 sigma margin
  uint32_t* mpre   = (uint32_t*)carve((size_t)E * 64);        // [E][32] bf16 (CSR slot order)
  float*    h      = (float*)carve((size_t)N * 32 * 4);       // [N][32] f32
  uint32_t* hAB    = (uint32_t*)carve((size_t)N * 128);       // [N][64] bf16 (hA|hB)
  float*    w1n    = (float*)carve(4 * 2048 * 4);             // [l][k][o]
  float*    w1c    = (float*)carve(4 * 32 * 4);               // [l][d]
  float*    ss     = (float*)carve(64 * 4);
  float*    stats  = (float*)carve((size_t)NBLK * 64 * 4);
  int*      cnt    = (int*)carve((size_t)N * 4);
  int*      rowptr = (int*)carve((size_t)N * 4);
  int*      bsum   = (int*)carve(256 * 4);
  int*      gcur   = (int*)carve(8 * 4);                      // bucket cursors
  uint32_t* b0     = (uint32_t*)carve((size_t)8 * cap * 4);   // (src<<14)|rank
  uint32_t* b1buf  = (uint32_t*)carve((size_t)8 * cap * 4);   // (d_local<<16)|ea_bf16
  float*    logits = (float*)carve((size_t)C * 4);
  int*      seg    = (int*)carve((size_t)C * 4);
  unsigned* segmax = (unsigned*)carve(NGRAPH * 4);
  float*    segsum = (float*)carve(NGRAPH * 4);
  (void)ws_size; (void)n_in; (void)out_size;

  // CSR metadata: one fused bucket+histogram+rank pass, then scan
  const int nb1 = (N + 1023) / 1024;
  k_zero32<<<(N + 255) / 256, 256, 0, stream>>>(cnt, N);
  k_zero32<<<1, 256, 0, stream>>>(gcur, 8);
  k_bucket<<<(E + CHUNK - 1) / CHUNK, 256, 0, stream>>>(src, dstp, eattr, gcur, cnt,
                                                        b0, b1buf, E, pstep, cap);
  k_scan1<<<nb1, 256, 0, stream>>>(cnt, rowptr, bsum, N);
  k_scan2<<<1, 256, 0, stream>>>(bsum, nb1);
  k_scan3<<<(N + 255) / 256, 256, 0, stream>>>(rowptr, bsum, N);

  k_prep<<<33, 256, 0, stream>>>(w1, w1n, w1c);
  k_initnode<<<(N * 64 + 255) / 256, 256, 0, stream>>>(x, wi, bi, w1n, h,
                                                       (unsigned short*)hAB, N);

  for (int l = 0; l < 4; l++) {
    k_combine<<<NBLK, 256, 0, stream>>>(hAB, b0, b1buf, gcur, rowptr, w1c + l * 32,
                                        mpre, stats, pstep, cap);
    k_finalize<<<32, 256, 0, stream>>>(stats, NBLK, E, g1 + l * 32, bb1 + l * 32, ss);
    k_gemm2m<<<NBLK, 256, 0, stream>>>(mpre, ss, w2 + l * 1024, stats, E);
    k_finalize<<<32, 256, 0, stream>>>(stats, NBLK, E, g2 + l * 32, bb2 + l * 32, ss);
    k_agg<<<(N + 7) / 8, 256, 0, stream>>>((const unsigned short*)mpre, rowptr, cnt,
                                           ss, h, N);
    if (l < 3)
      k_node<<<(N * 64 + 255) / 256, 256, 0, stream>>>(h, w1n + (l + 1) * 2048,
                                                       (unsigned short*)hAB, N);
  }

  k_initseg<<<(NGRAPH + 255) / 256, 256, 0, stream>>>(segmax, segsum);
  k_logits<<<(C + 255) / 256, 256, 0, stream>>>(h, cand, batch, wout, bout,
                                                logits, seg, segmax, C);
  k_expsum<<<(C + 255) / 256, 256, 0, stream>>>(logits, seg, segmax, segsum, C);
  k_out<<<(C + 255) / 256, 256, 0, stream>>>(logits, seg, segmax, segsum, (float*)d_out, C);
}

// Round 19
// 749.211 us; speedup vs baseline: 1.1034x; 1.0485x over previous
//
#include <hip/hip_runtime.h>
#include <stdint.h>

#define NGRAPH 1000

typedef __attribute__((ext_vector_type(8))) short short8;
typedef __attribute__((ext_vector_type(4))) float f32x4;

// ---------- helpers ----------
static __device__ __forceinline__ uint32_t pack2_bf16(float a, float b) {
  uint32_t ua = __float_as_uint(a), ub = __float_as_uint(b);
  ua = (ua + 0x7fffu + ((ua >> 16) & 1u)) >> 16;   // RNE
  ub = (ub + 0x7fffu + ((ub >> 16) & 1u)) >> 16;
  return ua | (ub << 16);
}
static __device__ __forceinline__ unsigned short f2bf(float x) {
  uint32_t u = __float_as_uint(x);
  u = (u + 0x7fffu + ((u >> 16) & 1u)) >> 16;
  return (unsigned short)u;
}
static __device__ __forceinline__ float bf2f(unsigned short u) {
  return __uint_as_float(((uint32_t)u) << 16);
}
union frag_u { short8 v; uint32_t u[4]; };

// ---------- prep: w1n[l][k][o] (o<32: W1a[o][k], o>=32: W1b[o-32][k]), w1c[l][d]=W1[d][64] ----------
__global__ __launch_bounds__(256) void k_prep(const float* __restrict__ w1,
                                              float* __restrict__ w1n,
                                              float* __restrict__ w1c) {
  int t = blockIdx.x * 256 + threadIdx.x;
  if (t < 4 * 2048) {
    int l = t >> 11, r = t & 2047, k = r >> 6, o = r & 63;
    w1n[t] = (o < 32) ? w1[l * 2080 + o * 65 + k]
                      : w1[l * 2080 + (o - 32) * 65 + (k + 32)];
  } else if (t < 4 * 2048 + 4 * 32) {
    int u = t - 4 * 2048;
    int l = u >> 5, d = u & 31;
    w1c[u] = w1[l * 2080 + d * 65 + 64];
  }
}

// ---------- zero cnt[N] and gcur[8] in one launch ----------
__global__ __launch_bounds__(256) void k_zeros(int* __restrict__ cnt,
                                               int* __restrict__ gcur, int n) {
  int t = blockIdx.x * 256 + threadIdx.x;
  if (t < n) cnt[t] = 0;
  if (t < 8) gcur[t] = 0;
}

// Single pass: bucket edges by dst partition AND compute global per-node rank
// (fused histogram). Bucket record is 8B/edge:
//   b0 = (src << 14) | rank        (src < 2^17, rank < 2^14)
//   b1 = (d_local << 16) | ea_bf16 (d_local < pstep <= 2^14)
// NOTE (r17 evidence): k_bucket is bound by device-scope atomic RMW throughput
// (~20 G/s), NOT latency — occupancy 27%->55% left dur unchanged. CHUNK=2048.
#define CHUNK 2048
__global__ __launch_bounds__(256) void k_bucket(const int* __restrict__ src,
                                                const int* __restrict__ dst,
                                                const float* __restrict__ ea,
                                                int* __restrict__ gcur,
                                                int* __restrict__ cnt,
                                                uint32_t* __restrict__ b0,
                                                uint32_t* __restrict__ b1,
                                                int E, int pstep, int cap) {
  __shared__ int lcnt[8], lbase[8];
  const int t = threadIdx.x;
  const int base = blockIdx.x * CHUNK;
  if (t < 8) lcnt[t] = 0;
  __syncthreads();
  int ps[8];
  uint32_t w0[8], w1[8];
#pragma unroll
  for (int j = 0; j < 8; j++) {
    int e = base + j * 256 + t;
    bool ok = e < E;
    int d = ok ? dst[e] : 0;
    int s = ok ? src[e] : 0;
    float eav = ok ? ea[e] : 0.f;
    int g = d / pstep;
    ps[j] = ok ? g : -1;
    if (ok) {
      int rank = atomicAdd(cnt + d, 1);            // global per-node rank + histogram
      w0[j] = ((uint32_t)s << 14) | (uint32_t)(rank & 16383);
      w1[j] = ((uint32_t)(d - g * pstep) << 16) | (uint32_t)f2bf(eav);
      atomicAdd(&lcnt[g], 1);
    }
  }
  __syncthreads();
  if (t < 8) lbase[t] = atomicAdd(&gcur[t], lcnt[t]);
  __syncthreads();
  if (t < 8) lcnt[t] = lbase[t];   // reuse as block-local cursor
  __syncthreads();
#pragma unroll
  for (int j = 0; j < 8; j++) {
    if (ps[j] >= 0) {
      int pos = atomicAdd(&lcnt[ps[j]], 1);
      if (pos < cap) {   // statistically impossible overflow guard
        size_t idx = (size_t)ps[j] * cap + pos;
        b0[idx] = w0[j];
        b1[idx] = w1[j];
      }
    }
  }
}

__global__ __launch_bounds__(256) void k_scan1(const int* __restrict__ in,
                                               int* __restrict__ out,
                                               int* __restrict__ bsum, int n) {
  __shared__ int sh[256];
  const int t = threadIdx.x;
  const int idx = blockIdx.x * 1024 + t * 4;
  int v[4];
#pragma unroll
  for (int j = 0; j < 4; j++) v[j] = (idx + j < n) ? in[idx + j] : 0;
  int tsum = v[0] + v[1] + v[2] + v[3];
  sh[t] = tsum;
  __syncthreads();
#pragma unroll
  for (int ofs = 1; ofs < 256; ofs <<= 1) {
    int x = (t >= ofs) ? sh[t - ofs] : 0;
    __syncthreads();
    sh[t] += x;
    __syncthreads();
  }
  int run = sh[t] - tsum;
  if (t == 255) bsum[blockIdx.x] = sh[255];
#pragma unroll
  for (int j = 0; j < 4; j++) {
    if (idx + j < n) out[idx + j] = run;
    run += v[j];
  }
}
__global__ __launch_bounds__(256) void k_scan2(int* __restrict__ bsum, int nb) {
  __shared__ int sh[256];
  const int t = threadIdx.x;
  int val = (t < nb) ? bsum[t] : 0;
  sh[t] = val;
  __syncthreads();
#pragma unroll
  for (int ofs = 1; ofs < 256; ofs <<= 1) {
    int x = (t >= ofs) ? sh[t - ofs] : 0;
    __syncthreads();
    sh[t] += x;
    __syncthreads();
  }
  if (t < nb) bsum[t] = sh[t] - val;
}
__global__ __launch_bounds__(256) void k_scan3(int* __restrict__ rowptr,
                                               const int* __restrict__ bsum, int n) {
  int t = blockIdx.x * 256 + threadIdx.x;
  if (t >= n) return;
  rowptr[t] = rowptr[t] + bsum[t >> 10];
}

// ---------- fused init+node (layer 0): one wave per node ----------
__global__ __launch_bounds__(256) void k_initnode(const float* __restrict__ x,
                                                  const float* __restrict__ wi,
                                                  const float* __restrict__ bi,
                                                  const float* __restrict__ w1n,
                                                  float* __restrict__ h,
                                                  unsigned short* __restrict__ hAB, int N) {
  const int wid = (blockIdx.x * 256 + threadIdx.x) >> 6;
  const int lane = threadIdx.x & 63;
  if (wid >= N) return;
  const int n = __builtin_amdgcn_readfirstlane(wid);
  const int d = lane & 31;
  const float x0 = x[2 * n], x1 = x[2 * n + 1];   // wave-uniform -> s_load
  const float hval = fmaf(x0, wi[2 * d], fmaf(x1, wi[2 * d + 1], bi[d]));
  if (lane < 32) h[(size_t)n * 32 + lane] = hval;
  float acc = 0.f;
#pragma unroll
  for (int k = 0; k < 32; k++)
    acc = fmaf(__shfl(hval, k, 64), w1n[k * 64 + lane], acc);
  hAB[(size_t)n * 64 + lane] = f2bf(acc);
}

// ---------- per-node factor (layers 1..3): one wave per node ----------
// (b1 dropped: column-constant bias cancels exactly through training-mode BN)
__global__ __launch_bounds__(256) void k_node(const float* __restrict__ h,
                                              const float* __restrict__ w1n,
                                              unsigned short* __restrict__ hAB, int N) {
  const int wid = (blockIdx.x * 256 + threadIdx.x) >> 6;
  const int lane = threadIdx.x & 63;
  if (wid >= N) return;
  const int n = __builtin_amdgcn_readfirstlane(wid);
  const float* hn = h + (size_t)n * 32;   // wave-uniform base -> s_load
  float acc = 0.f;
#pragma unroll
  for (int k = 0; k < 32; k++) acc = fmaf(hn[k], w1n[k * 64 + lane], acc);
  hAB[(size_t)n * 64 + lane] = f2bf(acc);
}

// ---------- pass A (4 lanes per edge): mpre[rowptr[d]+rank] = hA[d]+hB[src]+ea*w1c ----------
__global__ __launch_bounds__(256) void k_combine(
    const uint32_t* __restrict__ hAB, const uint32_t* __restrict__ b0,
    const uint32_t* __restrict__ b1, const int* __restrict__ gcur,
    const int* __restrict__ rowptr, const float* __restrict__ w1c,
    uint32_t* __restrict__ mpre, float* __restrict__ stats, int pstep, int cap) {
  const int t = threadIdx.x;
  const int r = t & 3;                    // sub-lane: channels [8r, 8r+8)
  float ssum[8], ssq[8];
#pragma unroll
  for (int q = 0; q < 8; q++) { ssum[q] = 0.f; ssq[q] = 0.f; }
  float wc[8];
#pragma unroll
  for (int j = 0; j < 8; j++) wc[j] = w1c[8 * r + j];

  const int gstride = (gridDim.x * blockDim.x) >> 2;
  const int eg0 = (blockIdx.x * blockDim.x + t) >> 2;
  for (int g = 0; g < 8; g++) {
    const int len = gcur[g];
    const size_t o = (size_t)g * cap;
    for (int i = eg0; i < len; i += gstride) {
      const uint32_t w0 = b0[o + i];      // 4 lanes same addr -> broadcast
      const uint32_t w1 = b1[o + i];
      const int vs = (int)(w0 >> 14);
      const int rank = (int)(w0 & 16383u);
      const int d = g * pstep + (int)(w1 >> 16);
      const float eav = bf2f((unsigned short)(w1 & 0xffffu));
      const int pos = rowptr[d] + rank;
      const uint4 av = *(const uint4*)(hAB + (size_t)d * 32 + r * 4);        // hA chans 8r..8r+7
      const uint4 bv = *(const uint4*)(hAB + (size_t)vs * 32 + 16 + r * 4);  // hB chans 8r..8r+7
      const uint32_t ad[4] = {av.x, av.y, av.z, av.w};
      const uint32_t bd[4] = {bv.x, bv.y, bv.z, bv.w};
      float m[8];
#pragma unroll
      for (int p = 0; p < 4; p++) {
        float a0 = __uint_as_float(ad[p] << 16), a1 = __uint_as_float(ad[p] & 0xffff0000u);
        float bb0 = __uint_as_float(bd[p] << 16), bb1 = __uint_as_float(bd[p] & 0xffff0000u);
        m[2 * p]     = a0 + fmaf(eav, wc[2 * p],     bb0);
        m[2 * p + 1] = a1 + fmaf(eav, wc[2 * p + 1], bb1);
      }
      uint4 out = make_uint4(pack2_bf16(m[0], m[1]), pack2_bf16(m[2], m[3]),
                             pack2_bf16(m[4], m[5]), pack2_bf16(m[6], m[7]));
      *(uint4*)(mpre + (size_t)pos * 16 + r * 4) = out;   // 4 lanes -> one full 64B line
#pragma unroll
      for (int q = 0; q < 8; q++) { ssum[q] += m[q]; ssq[q] = fmaf(m[q], m[q], ssq[q]); }
    }
  }
  // reduce over the 16 lanes sharing the same r (channel block)
#pragma unroll
  for (int q = 0; q < 8; q++) {
#pragma unroll
    for (int msk = 4; msk <= 32; msk <<= 1) {
      ssum[q] += __shfl_xor(ssum[q], msk, 64);
      ssq[q]  += __shfl_xor(ssq[q],  msk, 64);
    }
  }
  __shared__ float red[4][64];
  const int lane = t & 63, wv = t >> 6;
  if (lane < 4) {
#pragma unroll
    for (int j = 0; j < 8; j++) {
      red[wv][lane * 8 + j]      = ssum[j];
      red[wv][32 + lane * 8 + j] = ssq[j];
    }
  }
  __syncthreads();
  if (t < 64)
    stats[(size_t)blockIdx.x * 64 + t] = red[0][t] + red[1][t] + red[2][t] + red[3][t];
}

// ---------- finalize (parallel): block q reduces col q (sum) and q+32 (sumsq) ----------
__global__ __launch_bounds__(256) void k_finalize(const float* __restrict__ stats, int nblk, int E,
                                                  const float* __restrict__ g,
                                                  const float* __restrict__ bb,
                                                  float* __restrict__ ss) {
  const int q = blockIdx.x;
  const int t = threadIdx.x;
  double s0 = 0.0, s1 = 0.0;
  for (int i = t; i < nblk; i += 256) {
    s0 += (double)stats[(size_t)i * 64 + q];
    s1 += (double)stats[(size_t)i * 64 + 32 + q];
  }
  __shared__ double r0[256], r1[256];
  r0[t] = s0; r1[t] = s1;
  __syncthreads();
#pragma unroll
  for (int m = 128; m >= 1; m >>= 1) {
    if (t < m) { r0[t] += r0[t + m]; r1[t] += r1[t + m]; }
    __syncthreads();
  }
  if (t == 0) {
    double invE = 1.0 / (double)E;
    double mu = r0[0] * invE;
    double var = r1[0] * invE - mu * mu;
    if (var < 0.0) var = 0.0;
    double sc = (double)g[q] / sqrt(var + 1e-5);
    ss[q] = (float)sc;
    ss[32 + q] = (float)((double)bb[q] - mu * sc);
  }
}

// ---------- pass B (MFMA): m1 = relu(bn1(m_pre)); m_pre = m1 @ W2^T ; stats ----------
__global__ __launch_bounds__(256) void k_gemm2m(
    uint32_t* __restrict__ mpre, const float* __restrict__ ss,
    const float* __restrict__ w2, float* __restrict__ stats, int E) {
  const int lane = threadIdx.x & 63;
  const int wv = threadIdx.x >> 6;
  const int row = lane & 15;
  const int kb = (lane >> 4) * 8;
  const int G = E >> 4;
  const int gstart = blockIdx.x * 4 + wv;
  const int gstride = gridDim.x * 4;

  float sc[8], sh[8];
#pragma unroll
  for (int j = 0; j < 8; j++) { sc[j] = ss[kb + j]; sh[j] = ss[32 + kb + j]; }

  frag_u b0, b1;
#pragma unroll
  for (int p = 0; p < 4; p++) {
    const float* wp0 = w2 + (size_t)row * 32 + kb + 2 * p;
    const float* wp1 = w2 + (size_t)(row + 16) * 32 + kb + 2 * p;
    b0.u[p] = pack2_bf16(wp0[0], wp0[1]);
    b1.u[p] = pack2_bf16(wp1[0], wp1[1]);
  }

  float sum0 = 0.f, sq0 = 0.f, sum1 = 0.f, sq1 = 0.f;
  unsigned short* mp16 = (unsigned short*)mpre;

  for (int g = gstart; g < G; g += gstride) {
    const int e0 = g << 4;
    const uint4 raw = *(const uint4*)(mpre + (size_t)(e0 + row) * 16 + (lane >> 4) * 4);
    float m[8];
    m[0] = __uint_as_float(raw.x << 16); m[1] = __uint_as_float(raw.x & 0xffff0000u);
    m[2] = __uint_as_float(raw.y << 16); m[3] = __uint_as_float(raw.y & 0xffff0000u);
    m[4] = __uint_as_float(raw.z << 16); m[5] = __uint_as_float(raw.z & 0xffff0000u);
    m[6] = __uint_as_float(raw.w << 16); m[7] = __uint_as_float(raw.w & 0xffff0000u);
    frag_u a;
#pragma unroll
    for (int p = 0; p < 4; p++) {
      float x0 = fmaxf(fmaf(m[2 * p],     sc[2 * p],     sh[2 * p]),     0.f);
      float x1 = fmaxf(fmaf(m[2 * p + 1], sc[2 * p + 1], sh[2 * p + 1]), 0.f);
      a.u[p] = pack2_bf16(x0, x1);
    }
    f32x4 z = {0.f, 0.f, 0.f, 0.f};
    f32x4 acc0 = __builtin_amdgcn_mfma_f32_16x16x32_bf16(a.v, b0.v, z, 0, 0, 0);
    f32x4 acc1 = __builtin_amdgcn_mfma_f32_16x16x32_bf16(a.v, b1.v, z, 0, 0, 0);
#pragma unroll
    for (int r = 0; r < 4; r++) {
      sum0 += acc0[r]; sq0 = fmaf(acc0[r], acc0[r], sq0);
      sum1 += acc1[r]; sq1 = fmaf(acc1[r], acc1[r], sq1);
      const size_t base = (size_t)(e0 + (lane >> 4) * 4 + r) * 32;
      mp16[base + row]      = f2bf(acc0[r]);
      mp16[base + row + 16] = f2bf(acc1[r]);
    }
  }

  sum0 += __shfl_xor(sum0, 16); sum0 += __shfl_xor(sum0, 32);
  sq0  += __shfl_xor(sq0, 16);  sq0  += __shfl_xor(sq0, 32);
  sum1 += __shfl_xor(sum1, 16); sum1 += __shfl_xor(sum1, 32);
  sq1  += __shfl_xor(sq1, 16);  sq1  += __shfl_xor(sq1, 32);
  __shared__ float red[4][64];
  if (lane < 16) {
    red[wv][row] = sum0;      red[wv][16 + row] = sum1;
    red[wv][32 + row] = sq0;  red[wv][48 + row] = sq1;
  }
  __syncthreads();
  if (threadIdx.x < 64) {
    int q = threadIdx.x;
    stats[(size_t)blockIdx.x * 64 + q] = red[0][q] + red[1][q] + red[2][q] + red[3][q];
  }
}

// ---------- pass C (gather, 4 lanes/row): h[n] += sum relu(bn2(mpre CSR rows)) ----------
// 32-lane group per node; lane l=4j+r loads uint4 (channels 8r..8r+7) of row j,
// stride 8 rows/iter -> 512B contiguous per group-step (was 2B/lane scalar).
__global__ __launch_bounds__(256) void k_agg(
    const uint32_t* __restrict__ mp32, const int* __restrict__ rowptr,
    const int* __restrict__ cnt, const float* __restrict__ ss,
    float* __restrict__ h, int N) {
  const int n = blockIdx.x * 8 + (threadIdx.x >> 5);
  if (n >= N) return;
  const int l = threadIdx.x & 31;
  const int j = l >> 2, r = l & 3;
  const int start = rowptr[n];
  const int deg = cnt[n];
  float sc[8], sh[8];
#pragma unroll
  for (int q = 0; q < 8; q++) { sc[q] = ss[8 * r + q]; sh[q] = ss[32 + 8 * r + q]; }
  float acc[8];
#pragma unroll
  for (int q = 0; q < 8; q++) acc[q] = 0.f;
  for (int row = j; row < deg; row += 8) {
    const uint4 v = *(const uint4*)(mp32 + (size_t)(start + row) * 16 + r * 4);
    const uint32_t vd[4] = {v.x, v.y, v.z, v.w};
#pragma unroll
    for (int p = 0; p < 4; p++) {
      float x0 = bf2f((unsigned short)(vd[p] & 0xffffu));
      float x1 = bf2f((unsigned short)(vd[p] >> 16));
      acc[2 * p]     += fmaxf(fmaf(x0, sc[2 * p],     sh[2 * p]),     0.f);
      acc[2 * p + 1] += fmaxf(fmaf(x1, sc[2 * p + 1], sh[2 * p + 1]), 0.f);
    }
  }
  // fold the 8 row-slots (lanes sharing r): masks 4,8,16 stay within the 32-group
#pragma unroll
  for (int q = 0; q < 8; q++) {
    acc[q] += __shfl_xor(acc[q], 4, 64);
    acc[q] += __shfl_xor(acc[q], 8, 64);
    acc[q] += __shfl_xor(acc[q], 16, 64);
  }
  if (j == 0) {   // lanes 0..3 of the group hold the totals for channels 8r..8r+7
    float4* hp = (float4*)(h + (size_t)n * 32 + r * 8);
    float4 a = hp[0], b = hp[1];
    a.x += acc[0]; a.y += acc[1]; a.z += acc[2]; a.w += acc[3];
    b.x += acc[4]; b.y += acc[5]; b.z += acc[6]; b.w += acc[7];
    hp[0] = a; hp[1] = b;
  }
}

// ---------- readout ----------
__global__ __launch_bounds__(256) void k_initseg(unsigned* __restrict__ segmax,
                                                 float* __restrict__ segsum) {
  int t = blockIdx.x * 256 + threadIdx.x;
  if (t < NGRAPH) { segmax[t] = 0u; segsum[t] = 0.f; }
}

__global__ __launch_bounds__(256) void k_logits(
    const float* __restrict__ h, const int* __restrict__ cand, const int* __restrict__ batch,
    const float* __restrict__ wout, const float* __restrict__ bout,
    float* __restrict__ logits, int* __restrict__ seg, unsigned* __restrict__ segmax, int C) {
  int t = blockIdx.x * 256 + threadIdx.x;
  if (t >= C) return;
  int node = cand[t];
  const float4* hp = (const float4*)(h + (size_t)node * 32);
  float acc = bout[0];
#pragma unroll
  for (int kc = 0; kc < 8; kc++) {
    float4 v = hp[kc];
    acc = fmaf(v.x, wout[kc * 4 + 0], acc);
    acc = fmaf(v.y, wout[kc * 4 + 1], acc);
    acc = fmaf(v.z, wout[kc * 4 + 2], acc);
    acc = fmaf(v.w, wout[kc * 4 + 3], acc);
  }
  logits[t] = acc;
  int s = batch[node];
  seg[t] = s;
  unsigned o = __float_as_uint(acc);
  o ^= (o >> 31) ? 0xFFFFFFFFu : 0x80000000u;
  atomicMax(segmax + s, o);
}

static __device__ __forceinline__ float o2f(unsigned o) {
  o ^= (o & 0x80000000u) ? 0x80000000u : 0xFFFFFFFFu;
  return __uint_as_float(o);
}

__global__ __launch_bounds__(256) void k_expsum(const float* __restrict__ logits,
                                                const int* __restrict__ seg,
                                                const unsigned* __restrict__ segmax,
                                                float* __restrict__ segsum, int C) {
  int t = blockIdx.x * 256 + threadIdx.x;
  if (t >= C) return;
  int s = seg[t];
  float mx = o2f(segmax[s]);
  atomicAdd(segsum + s, expf(logits[t] - mx));
}

__global__ __launch_bounds__(256) void k_out(const float* __restrict__ logits,
                                             const int* __restrict__ seg,
                                             const unsigned* __restrict__ segmax,
                                             const float* __restrict__ segsum,
                                             float* __restrict__ out, int C) {
  int t = blockIdx.x * 256 + threadIdx.x;
  if (t >= C) return;
  int s = seg[t];
  out[t] = logits[t] - (o2f(segmax[s]) + logf(segsum[s]));
}

// ---------- launch ----------
extern "C" void kernel_launch(void* const* d_in, const int* in_sizes, int n_in,
                              void* d_out, int out_size, void* d_ws, size_t ws_size,
                              hipStream_t stream) {
  const float* x     = (const float*)d_in[0];
  const int*   eidx  = (const int*)d_in[1];
  const float* eattr = (const float*)d_in[2];
  const int*   cand  = (const int*)d_in[3];
  const int*   batch = (const int*)d_in[4];
  const float* wi    = (const float*)d_in[5];
  const float* bi    = (const float*)d_in[6];
  const float* w1    = (const float*)d_in[7];
  const float* g1    = (const float*)d_in[9];
  const float* bb1   = (const float*)d_in[10];
  const float* w2    = (const float*)d_in[11];
  const float* g2    = (const float*)d_in[13];
  const float* bb2   = (const float*)d_in[14];
  const float* wout  = (const float*)d_in[15];
  const float* bout  = (const float*)d_in[16];
  // b1 (d_in[8]) and b2 (d_in[12]) cancel exactly through training-mode BN.

  const int N = in_sizes[4];
  const int E = in_sizes[2];
  const int C = in_sizes[3];
  const int* src  = eidx;
  const int* dstp = eidx + E;

  // workspace carve (~144 MB)
  char* ws = (char*)d_ws;
  size_t off = 0;
  auto carve = [&](size_t bytes) {
    void* p = ws + off;
    off = (off + bytes + 255) & ~(size_t)255;
    return p;
  };
  const int NBLK = 1024;
  const int pstep = (N + 7) / 8;
  const int cap = E / 8 + 8192;   // Binomial(E,1/8) sigma~420 -> ~19 sigma margin
  uint32_t* mpre   = (uint32_t*)carve((size_t)E * 64);        // [E][32] bf16 (CSR slot order)
  float*    h      = (float*)carve((size_t)N * 32 * 4);       // [N][32] f32
  uint32_t* hAB    = (uint32_t*)carve((size_t)N * 128);       // [N][64] bf16 (hA|hB)
  float*    w1n    = (float*)carve(4 * 2048 * 4);             // [l][k][o]
  float*    w1c    = (float*)carve(4 * 32 * 4);               // [l][d]
  float*    ss     = (float*)carve(64 * 4);
  float*    stats  = (float*)carve((size_t)NBLK * 64 * 4);
  int*      cnt    = (int*)carve((size_t)N * 4);
  int*      rowptr = (int*)carve((size_t)N * 4);
  int*      bsum   = (int*)carve(256 * 4);
  int*      gcur   = (int*)carve(8 * 4);                      // bucket cursors
  uint32_t* b0     = (uint32_t*)carve((size_t)8 * cap * 4);   // (src<<14)|rank
  uint32_t* b1buf  = (uint32_t*)carve((size_t)8 * cap * 4);   // (d_local<<16)|ea_bf16
  float*    logits = (float*)carve((size_t)C * 4);
  int*      seg    = (int*)carve((size_t)C * 4);
  unsigned* segmax = (unsigned*)carve(NGRAPH * 4);
  float*    segsum = (float*)carve(NGRAPH * 4);
  (void)ws_size; (void)n_in; (void)out_size;

  // CSR metadata: one fused bucket+histogram+rank pass, then scan
  const int nb1 = (N + 1023) / 1024;
  k_zeros<<<(N + 255) / 256, 256, 0, stream>>>(cnt, gcur, N);
  k_bucket<<<(E + CHUNK - 1) / CHUNK, 256, 0, stream>>>(src, dstp, eattr, gcur, cnt,
                                                        b0, b1buf, E, pstep, cap);
  k_scan1<<<nb1, 256, 0, stream>>>(cnt, rowptr, bsum, N);
  k_scan2<<<1, 256, 0, stream>>>(bsum, nb1);
  k_scan3<<<(N + 255) / 256, 256, 0, stream>>>(rowptr, bsum, N);

  k_prep<<<33, 256, 0, stream>>>(w1, w1n, w1c);
  k_initnode<<<(N * 64 + 255) / 256, 256, 0, stream>>>(x, wi, bi, w1n, h,
                                                       (unsigned short*)hAB, N);

  for (int l = 0; l < 4; l++) {
    k_combine<<<NBLK, 256, 0, stream>>>(hAB, b0, b1buf, gcur, rowptr, w1c + l * 32,
                                        mpre, stats, pstep, cap);
    k_finalize<<<32, 256, 0, stream>>>(stats, NBLK, E, g1 + l * 32, bb1 + l * 32, ss);
    k_gemm2m<<<NBLK, 256, 0, stream>>>(mpre, ss, w2 + l * 1024, stats, E);
    k_finalize<<<32, 256, 0, stream>>>(stats, NBLK, E, g2 + l * 32, bb2 + l * 32, ss);
    k_agg<<<(N + 7) / 8, 256, 0, stream>>>(mpre, rowptr, cnt, ss, h, N);
    if (l < 3)
      k_node<<<(N * 64 + 255) / 256, 256, 0, stream>>>(h, w1n + (l + 1) * 2048,
                                                       (unsigned short*)hAB, N);
  }

  k_initseg<<<(NGRAPH + 255) / 256, 256, 0, stream>>>(segmax, segsum);
  k_logits<<<(C + 255) / 256, 256, 0, stream>>>(h, cand, batch, wout, bout,
                                                logits, seg, segmax, C);
  k_expsum<<<(C + 255) / 256, 256, 0, stream>>>(logits, seg, segmax, segsum, C);
  k_out<<<(C + 255) / 256, 256, 0, stream>>>(logits, seg, segmax, segsum, (float*)d_out, C);
}